// Round 1
// baseline (3626.669 us; speedup 1.0000x reference)
//
#include <hip/hip_runtime.h>
#include <math.h>

#define BATCH 4
#define C 512
#define N 4096   // content spatial (64*64)
#define M 4096   // style spatial (64*64)

// ---------------------------------------------------------------------------
// K1: per-pixel linear (1x1 conv): out[x][o] = sum_c W[o][c]*in[c][x] + bias[o]
// in: [C][N] (one batch), W: [512][C], out: [N][512]
// tile: 32 x-values x 64 o-values, BK=32; 256 threads
// ---------------------------------------------------------------------------
__global__ __launch_bounds__(256) void linear_kernel(
    const float* __restrict__ in, const float* __restrict__ W,
    const float* __restrict__ bias, float* __restrict__ out)
{
    __shared__ float in_s[32][36];   // [k][x], padded (16B-aligned rows)
    __shared__ float W_s[64][33];    // [o][k]
    const int tid = threadIdx.x;
    const int x0 = blockIdx.x * 32;
    const int o0 = blockIdx.y * 64;
    const int o_lane = tid & 63;     // 0..63
    const int xg = tid >> 6;         // 0..3
    float acc[8];
    #pragma unroll
    for (int i = 0; i < 8; ++i) acc[i] = 0.f;

    for (int kc = 0; kc < C; kc += 32) {
        {
            int idx = tid;
            #pragma unroll
            for (int i = 0; i < 4; ++i) {   // 1024 elems, coalesced over x
                int k = idx >> 5, x = idx & 31;
                in_s[k][x] = in[(size_t)(kc + k) * N + x0 + x];
                idx += 256;
            }
        }
        {
            int idx = tid;
            #pragma unroll
            for (int i = 0; i < 8; ++i) {   // 2048 elems, coalesced over k
                int o = idx >> 5, k = idx & 31;
                W_s[o][k] = W[(size_t)(o0 + o) * C + kc + k];
                idx += 256;
            }
        }
        __syncthreads();
        #pragma unroll
        for (int k = 0; k < 32; ++k) {
            float w = W_s[o_lane][k];
            #pragma unroll
            for (int i = 0; i < 8; ++i)
                acc[i] = fmaf(w, in_s[k][xg * 8 + i], acc[i]);
        }
        __syncthreads();
    }
    float bo = bias[o0 + o_lane];
    #pragma unroll
    for (int i = 0; i < 8; ++i) {
        int x = xg * 8 + i;
        out[(size_t)(x0 + x) * 512 + o0 + o_lane] = acc[i] + bo;  // coalesced over o_lane
    }
}

// ---------------------------------------------------------------------------
// K2: logits: S[n][m] = sum_c A[n][c] * Bt[m][c]   (A=Fq [N][512], Bt=Gt [M][512])
// tile 64n x 64m, BK=32; 256 threads, 4x4 outputs per thread
// ---------------------------------------------------------------------------
__global__ __launch_bounds__(256) void logits_kernel(
    const float* __restrict__ A, const float* __restrict__ Bt,
    float* __restrict__ S)
{
    __shared__ float A_s[32][68];  // [k][n], row stride 272B: 16B aligned
    __shared__ float B_s[32][68];  // [k][m]
    const int tid = threadIdx.x;
    const int n0 = blockIdx.y * 64;
    const int m0 = blockIdx.x * 64;
    const int tn = tid & 15, tm = tid >> 4;
    float acc[4][4] = {};
    for (int kc = 0; kc < C; kc += 32) {
        int idx = tid;
        #pragma unroll
        for (int i = 0; i < 8; ++i) {
            int r = idx >> 5, k = idx & 31;   // coalesced over k (contiguous c)
            A_s[k][r] = A[(size_t)(n0 + r) * C + kc + k];
            B_s[k][r] = Bt[(size_t)(m0 + r) * C + kc + k];
            idx += 256;
        }
        __syncthreads();
        #pragma unroll
        for (int k = 0; k < 32; ++k) {
            float a[4], b[4];
            #pragma unroll
            for (int i = 0; i < 4; ++i) a[i] = A_s[k][tn * 4 + i];
            #pragma unroll
            for (int j = 0; j < 4; ++j) b[j] = B_s[k][tm * 4 + j];
            #pragma unroll
            for (int i = 0; i < 4; ++i)
                #pragma unroll
                for (int j = 0; j < 4; ++j)
                    acc[i][j] = fmaf(a[i], b[j], acc[i][j]);
        }
        __syncthreads();
    }
    #pragma unroll
    for (int i = 0; i < 4; ++i) {
        int n = n0 + tn * 4 + i;
        float4 v = make_float4(acc[i][0], acc[i][1], acc[i][2], acc[i][3]);
        *(float4*)&S[(size_t)n * M + m0 + tm * 4] = v;
    }
}

// ---------------------------------------------------------------------------
// K3: per-row max and sum(exp(x-max)) over M=4096; one block per row
// ---------------------------------------------------------------------------
__global__ __launch_bounds__(256) void rowstat_kernel(
    const float* __restrict__ S, float* __restrict__ rmax, float* __restrict__ rsum)
{
    const int n = blockIdx.x;
    const int tid = threadIdx.x;
    const float* row = S + (size_t)n * M;
    float v[16];
    #pragma unroll
    for (int i = 0; i < 16; ++i) v[i] = row[tid + i * 256];
    float lm = -INFINITY;
    #pragma unroll
    for (int i = 0; i < 16; ++i) lm = fmaxf(lm, v[i]);
    #pragma unroll
    for (int off = 32; off > 0; off >>= 1) lm = fmaxf(lm, __shfl_xor(lm, off, 64));
    __shared__ float red[4];
    __shared__ float redsum[4];
    const int wid = tid >> 6, lane = tid & 63;
    if (lane == 0) red[wid] = lm;
    __syncthreads();
    const float rm = fmaxf(fmaxf(red[0], red[1]), fmaxf(red[2], red[3]));
    float ls = 0.f;
    #pragma unroll
    for (int i = 0; i < 16; ++i) ls += __expf(v[i] - rm);
    #pragma unroll
    for (int off = 32; off > 0; off >>= 1) ls += __shfl_xor(ls, off, 64);
    if (lane == 0) redsum[wid] = ls;
    __syncthreads();
    if (tid == 0) {
        rmax[n] = rm;
        rsum[n] = redsum[0] + redsum[1] + redsum[2] + redsum[3];
    }
}

// ---------------------------------------------------------------------------
// K4: mean/std: acc_m[n][c] = sum_m p * V[m][c], acc_2 = sum_m p * V^2,
//     p = exp(S[n][m]-rmax[n]); then /rsum, std=sqrt(relu(m2-mean^2)).
// tile 64n x 64c, K=M chunked by 32; 256 threads, 4x4 per thread, dual acc
// ---------------------------------------------------------------------------
__global__ __launch_bounds__(256) void apply_kernel(
    const float* __restrict__ S, const float* __restrict__ V,
    const float* __restrict__ rmax, const float* __restrict__ rsum,
    float* __restrict__ meanw, float* __restrict__ stdw)
{
    __shared__ float P_s[32][68];   // [m][n]
    __shared__ float V_s[32][68];   // [m][c]
    __shared__ float rmax_s[64];
    const int tid = threadIdx.x;
    const int n0 = blockIdx.y * 64;
    const int c0 = blockIdx.x * 64;
    if (tid < 64) rmax_s[tid] = rmax[n0 + tid];
    __syncthreads();
    const int tn = tid & 15, tc = tid >> 4;
    float accm[4][4] = {};
    float acc2[4][4] = {};
    for (int mc = 0; mc < M; mc += 32) {
        {
            int idx = tid;
            #pragma unroll
            for (int i = 0; i < 8; ++i) {   // S: coalesced over m (k)
                int r = idx >> 5, k = idx & 31;
                P_s[k][r] = __expf(S[(size_t)(n0 + r) * M + mc + k] - rmax_s[r]);
                idx += 256;
            }
        }
        {
            int idx = tid;
            #pragma unroll
            for (int i = 0; i < 8; ++i) {   // V: coalesced over c
                int k = idx >> 6, cc = idx & 63;
                V_s[k][cc] = V[(size_t)(mc + k) * C + c0 + cc];
                idx += 256;
            }
        }
        __syncthreads();
        #pragma unroll
        for (int k = 0; k < 32; ++k) {
            float a[4], b[4], b2[4];
            #pragma unroll
            for (int i = 0; i < 4; ++i) a[i] = P_s[k][tn * 4 + i];
            #pragma unroll
            for (int j = 0; j < 4; ++j) { b[j] = V_s[k][tc * 4 + j]; b2[j] = b[j] * b[j]; }
            #pragma unroll
            for (int i = 0; i < 4; ++i)
                #pragma unroll
                for (int j = 0; j < 4; ++j) {
                    accm[i][j] = fmaf(a[i], b[j],  accm[i][j]);
                    acc2[i][j] = fmaf(a[i], b2[j], acc2[i][j]);
                }
        }
        __syncthreads();
    }
    #pragma unroll
    for (int i = 0; i < 4; ++i) {
        int n = n0 + tn * 4 + i;
        float inv = 1.0f / rsum[n];
        float4 mnv, sdv;
        float* mp = (float*)&mnv;
        float* sp = (float*)&sdv;
        #pragma unroll
        for (int j = 0; j < 4; ++j) {
            float mn = accm[i][j] * inv;
            float m2 = acc2[i][j] * inv;
            float var = m2 - mn * mn;
            mp[j] = mn;
            sp[j] = sqrtf(fmaxf(var, 0.f));
        }
        *(float4*)&meanw[(size_t)n * C + c0 + tc * 4] = mnv;
        *(float4*)&stdw [(size_t)n * C + c0 + tc * 4] = sdv;
    }
}

// ---------------------------------------------------------------------------
// K5: instance-norm stats per channel: mu, 1/sqrt(var_unbiased + 1e-5)
// one block per channel; content row = [N] contiguous
// ---------------------------------------------------------------------------
__global__ __launch_bounds__(256) void mvn_kernel(
    const float* __restrict__ content, float* __restrict__ mu, float* __restrict__ rstd)
{
    const int c = blockIdx.x;
    const int tid = threadIdx.x;
    const float* row = content + (size_t)c * N;
    float s = 0.f, ss = 0.f;
    for (int i = tid; i < N; i += 256) {
        float v = row[i];
        s += v;
        ss = fmaf(v, v, ss);
    }
    #pragma unroll
    for (int off = 32; off > 0; off >>= 1) {
        s  += __shfl_xor(s,  off, 64);
        ss += __shfl_xor(ss, off, 64);
    }
    __shared__ float rs[4], rss[4];
    const int wid = tid >> 6, lane = tid & 63;
    if (lane == 0) { rs[wid] = s; rss[wid] = ss; }
    __syncthreads();
    if (tid == 0) {
        float st = rs[0] + rs[1] + rs[2] + rs[3];
        float sst = rss[0] + rss[1] + rss[2] + rss[3];
        float m = st / (float)N;
        float var = (sst - st * st / (float)N) / (float)(N - 1);
        mu[c] = m;
        rstd[c] = rsqrtf(var + 1e-5f);
    }
}

// ---------------------------------------------------------------------------
// K6: out[c][n] = stdw[n][c] * (content[c][n]-mu[c])*rstd[c] + meanw[n][c]
// 32x32 tile transpose of mean/std through LDS; coalesced reads/writes
// ---------------------------------------------------------------------------
__global__ __launch_bounds__(256) void final_kernel(
    const float* __restrict__ content, const float* __restrict__ meanw,
    const float* __restrict__ stdw, const float* __restrict__ mu,
    const float* __restrict__ rstd, float* __restrict__ out)
{
    __shared__ float mn_s[32][33], sd_s[32][33];
    const int tid = threadIdx.x;
    const int n0 = blockIdx.x * 32;
    const int c0 = blockIdx.y * 32;
    const int tx = tid & 31, ty = tid >> 5;   // ty: 0..7
    #pragma unroll
    for (int i = 0; i < 4; ++i) {
        int n = ty + i * 8;                    // 0..31
        mn_s[tx][n] = meanw[(size_t)(n0 + n) * C + c0 + tx];  // coalesced over c
        sd_s[tx][n] = stdw [(size_t)(n0 + n) * C + c0 + tx];
    }
    __syncthreads();
    #pragma unroll
    for (int i = 0; i < 4; ++i) {
        int c = ty + i * 8;                    // 0..31 local channel
        float m = mu[c0 + c], r = rstd[c0 + c];
        size_t off = (size_t)(c0 + c) * N + n0 + tx;
        float x = content[off];                // coalesced over n
        out[off] = sd_s[c][tx] * (x - m) * r + mn_s[c][tx];
    }
}

// ---------------------------------------------------------------------------
extern "C" void kernel_launch(void* const* d_in, const int* in_sizes, int n_in,
                              void* d_out, int out_size, void* d_ws, size_t ws_size,
                              hipStream_t stream)
{
    const float* content = (const float*)d_in[0];
    const float* style   = (const float*)d_in[1];
    const float* ckey    = (const float*)d_in[2];
    const float* skey    = (const float*)d_in[3];
    const float* Wf      = (const float*)d_in[4];
    const float* bf      = (const float*)d_in[5];
    const float* Wg      = (const float*)d_in[6];
    const float* bg      = (const float*)d_in[7];
    const float* Wh      = (const float*)d_in[8];
    const float* bh      = (const float*)d_in[9];
    float* out = (float*)d_out;

    // workspace layout (floats): per-batch buffers reused across the 4 batches
    float* ws   = (float*)d_ws;
    float* Fq   = ws;                          // [N][C]   8 MB
    float* Gt   = Fq   + (size_t)N * C;        // [M][C]   8 MB
    float* Vv   = Gt   + (size_t)M * C;        // [M][C]   8 MB
    float* S    = Vv   + (size_t)M * C;        // [N][M]  64 MB
    float* rmax = S    + (size_t)N * M;        // [N]
    float* rsum = rmax + N;                    // [N]
    float* meanw= rsum + N;                    // [N][C]   8 MB
    float* stdw = meanw+ (size_t)N * C;        // [N][C]   8 MB
    float* mu   = stdw + (size_t)N * C;        // [C]
    float* rstd = mu   + C;                    // [C]

    for (int b = 0; b < BATCH; ++b) {
        const size_t fo = (size_t)b * C * N;
        linear_kernel<<<dim3(N / 32, 512 / 64), 256, 0, stream>>>(ckey + fo,  Wf, bf, Fq);
        linear_kernel<<<dim3(M / 32, 512 / 64), 256, 0, stream>>>(skey + fo,  Wg, bg, Gt);
        linear_kernel<<<dim3(M / 32, 512 / 64), 256, 0, stream>>>(style + fo, Wh, bh, Vv);
        logits_kernel<<<dim3(M / 64, N / 64), 256, 0, stream>>>(Fq, Gt, S);
        rowstat_kernel<<<dim3(N), 256, 0, stream>>>(S, rmax, rsum);
        apply_kernel<<<dim3(512 / 64, N / 64), 256, 0, stream>>>(S, Vv, rmax, rsum, meanw, stdw);
        mvn_kernel<<<dim3(512), 256, 0, stream>>>(content + fo, mu, rstd);
        final_kernel<<<dim3(N / 32, 512 / 32), 256, 0, stream>>>(content + fo, meanw, stdw, mu, rstd, out + fo);
    }
}

// Round 2
// 1706.789 us; speedup vs baseline: 2.1248x; 2.1248x over previous
//
#include <hip/hip_runtime.h>
#include <math.h>

#define BATCH 4
#define C 512
#define N 4096   // content spatial (64*64)
#define M 4096   // style spatial (64*64)

typedef __attribute__((ext_vector_type(8))) short short8;
typedef __attribute__((ext_vector_type(8))) __bf16 bf16x8;
typedef __attribute__((ext_vector_type(4))) float f32x4;

static __device__ __forceinline__ unsigned short f2bf(float x) {
    unsigned u = __float_as_uint(x);
    u += 0x7fff + ((u >> 16) & 1);          // round-to-nearest-even
    return (unsigned short)(u >> 16);
}
static __device__ __forceinline__ float bf2f(unsigned short h) {
    return __uint_as_float(((unsigned)h) << 16);
}
static __device__ __forceinline__ f32x4 mfma_bf16(short8 a, short8 b, f32x4 c) {
    return __builtin_amdgcn_mfma_f32_16x16x32_bf16(
        __builtin_bit_cast(bf16x8, a), __builtin_bit_cast(bf16x8, b), c, 0, 0, 0);
}

// ---------------------------------------------------------------------------
// K1a: linear writing bf16 hi/lo split: out[x][o], o fastest. For Fq and Gt.
// ---------------------------------------------------------------------------
__global__ __launch_bounds__(256) void linear_hilo_kernel(
    const float* __restrict__ in, const float* __restrict__ W,
    const float* __restrict__ bias, unsigned short* __restrict__ out_hi,
    unsigned short* __restrict__ out_lo)
{
    __shared__ float in_s[32][36];
    __shared__ float W_s[64][33];
    const int tid = threadIdx.x;
    const int x0 = blockIdx.x * 32;
    const int o0 = blockIdx.y * 64;
    const int o_lane = tid & 63;
    const int xg = tid >> 6;
    float acc[8];
    #pragma unroll
    for (int i = 0; i < 8; ++i) acc[i] = 0.f;

    for (int kc = 0; kc < C; kc += 32) {
        {
            int idx = tid;
            #pragma unroll
            for (int i = 0; i < 4; ++i) {
                int k = idx >> 5, x = idx & 31;
                in_s[k][x] = in[(size_t)(kc + k) * N + x0 + x];
                idx += 256;
            }
        }
        {
            int idx = tid;
            #pragma unroll
            for (int i = 0; i < 8; ++i) {
                int o = idx >> 5, k = idx & 31;
                W_s[o][k] = W[(size_t)(o0 + o) * C + kc + k];
                idx += 256;
            }
        }
        __syncthreads();
        #pragma unroll
        for (int k = 0; k < 32; ++k) {
            float w = W_s[o_lane][k];
            #pragma unroll
            for (int i = 0; i < 8; ++i)
                acc[i] = fmaf(w, in_s[k][xg * 8 + i], acc[i]);
        }
        __syncthreads();
    }
    float bo = bias[o0 + o_lane];
    #pragma unroll
    for (int i = 0; i < 8; ++i) {
        int x = xg * 8 + i;
        float v = acc[i] + bo;
        unsigned short h = f2bf(v);
        unsigned short l = f2bf(v - bf2f(h));
        size_t off = (size_t)(x0 + x) * C + o0 + o_lane;
        out_hi[off] = h;
        out_lo[off] = l;
    }
}

// ---------------------------------------------------------------------------
// K1b: V-linear writing TRANSPOSED bf16: vhT[c][m], v2hT=hi(vh^2), v2lT=lo.
// tile: 64 m (lane) x 32 c (4 groups x 8)
// ---------------------------------------------------------------------------
__global__ __launch_bounds__(256) void linear_vT_kernel(
    const float* __restrict__ in, const float* __restrict__ W,
    const float* __restrict__ bias,
    unsigned short* __restrict__ vhT, unsigned short* __restrict__ v2hT,
    unsigned short* __restrict__ v2lT)
{
    __shared__ float in_s[32][64];   // [k][m]
    __shared__ float W_s[32][33];    // [o][k]
    const int tid = threadIdx.x;
    const int m0 = blockIdx.x * 64;
    const int o0 = blockIdx.y * 32;
    const int lane = tid & 63, og = tid >> 6;
    float acc[8];
    #pragma unroll
    for (int i = 0; i < 8; ++i) acc[i] = 0.f;

    for (int kc = 0; kc < C; kc += 32) {
        #pragma unroll
        for (int i = 0; i < 8; ++i) {
            int idx = tid + i * 256;
            int k = idx >> 6, x = idx & 63;
            in_s[k][x] = in[(size_t)(kc + k) * N + m0 + x];
        }
        #pragma unroll
        for (int i = 0; i < 4; ++i) {
            int idx = tid + i * 256;
            int o = idx >> 5, k = idx & 31;
            W_s[o][k] = W[(size_t)(o0 + o) * C + kc + k];
        }
        __syncthreads();
        #pragma unroll
        for (int k = 0; k < 32; ++k) {
            float xv = in_s[k][lane];
            #pragma unroll
            for (int i = 0; i < 8; ++i)
                acc[i] = fmaf(W_s[og * 8 + i][k], xv, acc[i]);   // W_s broadcast per wave
        }
        __syncthreads();
    }
    #pragma unroll
    for (int i = 0; i < 8; ++i) {
        int o = o0 + og * 8 + i;
        float v = acc[i] + bias[o];
        unsigned short vh = f2bf(v);
        float vhf = bf2f(vh);
        float vsq = vhf * vhf;
        unsigned short v2h = f2bf(vsq);
        unsigned short v2l = f2bf(vsq - bf2f(v2h));
        size_t off = (size_t)o * M + m0 + lane;
        vhT[off] = vh;
        v2hT[off] = v2h;
        v2lT[off] = v2l;
    }
}

// ---------------------------------------------------------------------------
// K2: logits MFMA: S[n][m] = Ah.BhT + Ah.BlT + Al.BhT  (hi/lo bf16 split)
// block tile 128n x 128m, BK=32, 4 waves (2x2), wave tile 64x64 (4x4 MFMAs)
// ---------------------------------------------------------------------------
__global__ __launch_bounds__(256) void logits_mfma_kernel(
    const unsigned short* __restrict__ Ah, const unsigned short* __restrict__ Al,
    const unsigned short* __restrict__ Bh, const unsigned short* __restrict__ Bl,
    float* __restrict__ S)
{
    __shared__ __align__(16) unsigned short Ah_s[128 * 40];
    __shared__ __align__(16) unsigned short Al_s[128 * 40];
    __shared__ __align__(16) unsigned short Bh_s[128 * 40];
    __shared__ __align__(16) unsigned short Bl_s[128 * 40];
    const int tid = threadIdx.x;
    const int n0 = blockIdx.y * 128, m0 = blockIdx.x * 128;
    const int w = tid >> 6, lane = tid & 63;
    const int wrow = w >> 1, wcol = w & 1;
    const int lr = lane & 15, q = lane >> 4;
    f32x4 acc[4][4];
    #pragma unroll
    for (int i = 0; i < 4; ++i)
        #pragma unroll
        for (int j = 0; j < 4; ++j)
            acc[i][j] = (f32x4){0.f, 0.f, 0.f, 0.f};

    for (int kc = 0; kc < C; kc += 32) {
        __syncthreads();
        #pragma unroll
        for (int it = 0; it < 2; ++it) {
            int idx = tid + it * 256;
            int row = idx >> 2, seg = idx & 3;
            int ldso = row * 40 + seg * 8;
            int go = kc + seg * 8;
            *(float4*)&Ah_s[ldso] = *(const float4*)&Ah[(size_t)(n0 + row) * C + go];
            *(float4*)&Al_s[ldso] = *(const float4*)&Al[(size_t)(n0 + row) * C + go];
            *(float4*)&Bh_s[ldso] = *(const float4*)&Bh[(size_t)(m0 + row) * C + go];
            *(float4*)&Bl_s[ldso] = *(const float4*)&Bl[(size_t)(m0 + row) * C + go];
        }
        __syncthreads();
        short8 ah[4], al[4], bh[4], bl[4];
        #pragma unroll
        for (int i = 0; i < 4; ++i) {
            int ro = (wrow * 64 + i * 16 + lr) * 40 + q * 8;
            int co = (wcol * 64 + i * 16 + lr) * 40 + q * 8;
            ah[i] = *(const short8*)&Ah_s[ro];
            al[i] = *(const short8*)&Al_s[ro];
            bh[i] = *(const short8*)&Bh_s[co];
            bl[i] = *(const short8*)&Bl_s[co];
        }
        #pragma unroll
        for (int i = 0; i < 4; ++i)
            #pragma unroll
            for (int j = 0; j < 4; ++j) {
                acc[i][j] = mfma_bf16(ah[i], bh[j], acc[i][j]);
                acc[i][j] = mfma_bf16(ah[i], bl[j], acc[i][j]);
                acc[i][j] = mfma_bf16(al[i], bh[j], acc[i][j]);
            }
    }
    #pragma unroll
    for (int i = 0; i < 4; ++i) {
        int nb = n0 + wrow * 64 + i * 16 + q * 4;
        #pragma unroll
        for (int j = 0; j < 4; ++j) {
            int m = m0 + wcol * 64 + j * 16 + lr;
            #pragma unroll
            for (int r = 0; r < 4; ++r)
                S[(size_t)(nb + r) * M + m] = acc[i][j][r];
        }
    }
}

// ---------------------------------------------------------------------------
// K3: row softmax -> bf16 P, rsum = sum of the ROUNDED p (consistency!)
// ---------------------------------------------------------------------------
__global__ __launch_bounds__(256) void rowstat_p_kernel(
    const float* __restrict__ S, unsigned short* __restrict__ P,
    float* __restrict__ rsum)
{
    const int n = blockIdx.x;
    const int tid = threadIdx.x;
    const float* row = S + (size_t)n * M;
    float v[16];
    #pragma unroll
    for (int i = 0; i < 16; ++i) v[i] = row[tid + i * 256];
    float lm = -INFINITY;
    #pragma unroll
    for (int i = 0; i < 16; ++i) lm = fmaxf(lm, v[i]);
    #pragma unroll
    for (int off = 32; off > 0; off >>= 1) lm = fmaxf(lm, __shfl_xor(lm, off, 64));
    __shared__ float red[4];
    __shared__ float redsum[4];
    const int wid = tid >> 6, lane = tid & 63;
    if (lane == 0) red[wid] = lm;
    __syncthreads();
    const float rm = fmaxf(fmaxf(red[0], red[1]), fmaxf(red[2], red[3]));
    float ls = 0.f;
    unsigned short* prow = P + (size_t)n * M;
    #pragma unroll
    for (int i = 0; i < 16; ++i) {
        float p = __expf(v[i] - rm);
        unsigned short pb = f2bf(p);
        prow[tid + i * 256] = pb;
        ls += bf2f(pb);
    }
    #pragma unroll
    for (int off = 32; off > 0; off >>= 1) ls += __shfl_xor(ls, off, 64);
    if (lane == 0) redsum[wid] = ls;
    __syncthreads();
    if (tid == 0) rsum[n] = redsum[0] + redsum[1] + redsum[2] + redsum[3];
}

// ---------------------------------------------------------------------------
// K4: apply MFMA: accm = P@vh, acc2 = P@v2h + P@v2l; mean/std epilogue.
// block tile 128n x 64c, BK=32, waves 2x2, wave tile 64n x 32c
// ---------------------------------------------------------------------------
__global__ __launch_bounds__(256) void apply_mfma_kernel(
    const unsigned short* __restrict__ P, const unsigned short* __restrict__ VhT,
    const unsigned short* __restrict__ V2hT, const unsigned short* __restrict__ V2lT,
    const float* __restrict__ rsum,
    float* __restrict__ meanw, float* __restrict__ stdw)
{
    __shared__ __align__(16) unsigned short P_s[128 * 40];
    __shared__ __align__(16) unsigned short Vh_s[64 * 40];
    __shared__ __align__(16) unsigned short V2h_s[64 * 40];
    __shared__ __align__(16) unsigned short V2l_s[64 * 40];
    const int tid = threadIdx.x;
    const int c0 = blockIdx.x * 64, n0 = blockIdx.y * 128;
    const int w = tid >> 6, lane = tid & 63;
    const int wrow = w >> 1, wcol = w & 1;
    const int lr = lane & 15, q = lane >> 4;
    f32x4 accm[4][2], acc2[4][2];
    #pragma unroll
    for (int i = 0; i < 4; ++i)
        #pragma unroll
        for (int j = 0; j < 2; ++j) {
            accm[i][j] = (f32x4){0.f, 0.f, 0.f, 0.f};
            acc2[i][j] = (f32x4){0.f, 0.f, 0.f, 0.f};
        }

    for (int mc = 0; mc < M; mc += 32) {
        __syncthreads();
        #pragma unroll
        for (int it = 0; it < 2; ++it) {
            int idx = tid + it * 256;
            int row = idx >> 2, seg = idx & 3;
            *(float4*)&P_s[row * 40 + seg * 8] =
                *(const float4*)&P[(size_t)(n0 + row) * M + mc + seg * 8];
        }
        {
            int row = tid >> 2, seg = tid & 3;
            int ldso = row * 40 + seg * 8;
            size_t go = (size_t)(c0 + row) * M + mc + seg * 8;
            *(float4*)&Vh_s[ldso]  = *(const float4*)&VhT[go];
            *(float4*)&V2h_s[ldso] = *(const float4*)&V2hT[go];
            *(float4*)&V2l_s[ldso] = *(const float4*)&V2lT[go];
        }
        __syncthreads();
        short8 a[4], b[2], b2h[2], b2l[2];
        #pragma unroll
        for (int i = 0; i < 4; ++i)
            a[i] = *(const short8*)&P_s[(wrow * 64 + i * 16 + lr) * 40 + q * 8];
        #pragma unroll
        for (int j = 0; j < 2; ++j) {
            int co = (wcol * 32 + j * 16 + lr) * 40 + q * 8;
            b[j]   = *(const short8*)&Vh_s[co];
            b2h[j] = *(const short8*)&V2h_s[co];
            b2l[j] = *(const short8*)&V2l_s[co];
        }
        #pragma unroll
        for (int i = 0; i < 4; ++i)
            #pragma unroll
            for (int j = 0; j < 2; ++j) {
                accm[i][j] = mfma_bf16(a[i], b[j],   accm[i][j]);
                acc2[i][j] = mfma_bf16(a[i], b2h[j], acc2[i][j]);
                acc2[i][j] = mfma_bf16(a[i], b2l[j], acc2[i][j]);
            }
    }
    #pragma unroll
    for (int i = 0; i < 4; ++i) {
        int nb = n0 + wrow * 64 + i * 16 + q * 4;
        #pragma unroll
        for (int j = 0; j < 2; ++j) {
            int c = c0 + wcol * 32 + j * 16 + lr;
            #pragma unroll
            for (int r = 0; r < 4; ++r) {
                int n = nb + r;
                float inv = 1.0f / rsum[n];
                float mn = accm[i][j][r] * inv;
                float m2 = acc2[i][j][r] * inv;
                float sd = sqrtf(fmaxf(m2 - mn * mn, 0.f));
                meanw[(size_t)n * C + c] = mn;
                stdw[(size_t)n * C + c]  = sd;
            }
        }
    }
}

// ---------------------------------------------------------------------------
// K5: instance-norm stats per channel (fp32, unchanged)
// ---------------------------------------------------------------------------
__global__ __launch_bounds__(256) void mvn_kernel(
    const float* __restrict__ content, float* __restrict__ mu, float* __restrict__ rstd)
{
    const int c = blockIdx.x;
    const int tid = threadIdx.x;
    const float* row = content + (size_t)c * N;
    float s = 0.f, ss = 0.f;
    for (int i = tid; i < N; i += 256) {
        float v = row[i];
        s += v;
        ss = fmaf(v, v, ss);
    }
    #pragma unroll
    for (int off = 32; off > 0; off >>= 1) {
        s  += __shfl_xor(s,  off, 64);
        ss += __shfl_xor(ss, off, 64);
    }
    __shared__ float rs[4], rss[4];
    const int wid = tid >> 6, lane = tid & 63;
    if (lane == 0) { rs[wid] = s; rss[wid] = ss; }
    __syncthreads();
    if (tid == 0) {
        float st = rs[0] + rs[1] + rs[2] + rs[3];
        float sst = rss[0] + rss[1] + rss[2] + rss[3];
        float m = st / (float)N;
        float var = (sst - st * st / (float)N) / (float)(N - 1);
        mu[c] = m;
        rstd[c] = rsqrtf(var + 1e-5f);
    }
}

// ---------------------------------------------------------------------------
// K6: final combine (fp32, unchanged)
// ---------------------------------------------------------------------------
__global__ __launch_bounds__(256) void final_kernel(
    const float* __restrict__ content, const float* __restrict__ meanw,
    const float* __restrict__ stdw, const float* __restrict__ mu,
    const float* __restrict__ rstd, float* __restrict__ out)
{
    __shared__ float mn_s[32][33], sd_s[32][33];
    const int tid = threadIdx.x;
    const int n0 = blockIdx.x * 32;
    const int c0 = blockIdx.y * 32;
    const int tx = tid & 31, ty = tid >> 5;
    #pragma unroll
    for (int i = 0; i < 4; ++i) {
        int n = ty + i * 8;
        mn_s[tx][n] = meanw[(size_t)(n0 + n) * C + c0 + tx];
        sd_s[tx][n] = stdw [(size_t)(n0 + n) * C + c0 + tx];
    }
    __syncthreads();
    #pragma unroll
    for (int i = 0; i < 4; ++i) {
        int c = ty + i * 8;
        float m = mu[c0 + c], r = rstd[c0 + c];
        size_t off = (size_t)(c0 + c) * N + n0 + tx;
        float x = content[off];
        out[off] = sd_s[c][tx] * (x - m) * r + mn_s[c][tx];
    }
}

// ---------------------------------------------------------------------------
extern "C" void kernel_launch(void* const* d_in, const int* in_sizes, int n_in,
                              void* d_out, int out_size, void* d_ws, size_t ws_size,
                              hipStream_t stream)
{
    const float* content = (const float*)d_in[0];
    const float* style   = (const float*)d_in[1];
    const float* ckey    = (const float*)d_in[2];
    const float* skey    = (const float*)d_in[3];
    const float* Wf      = (const float*)d_in[4];
    const float* bf      = (const float*)d_in[5];
    const float* Wg      = (const float*)d_in[6];
    const float* bg      = (const float*)d_in[7];
    const float* Wh      = (const float*)d_in[8];
    const float* bh      = (const float*)d_in[9];
    float* out = (float*)d_out;

    // workspace layout (bytes), per-batch buffers reused
    char* p = (char*)d_ws;
    float* S = (float*)p;                 p += (size_t)N * M * 4;   // 64 MB
    unsigned short* P = (unsigned short*)p; p += (size_t)N * M * 2; // 32 MB
    unsigned short* Fh = (unsigned short*)p; p += (size_t)N * C * 2;
    unsigned short* Fl = (unsigned short*)p; p += (size_t)N * C * 2;
    unsigned short* Gh = (unsigned short*)p; p += (size_t)M * C * 2;
    unsigned short* Gl = (unsigned short*)p; p += (size_t)M * C * 2;
    unsigned short* VhT  = (unsigned short*)p; p += (size_t)C * M * 2;
    unsigned short* V2hT = (unsigned short*)p; p += (size_t)C * M * 2;
    unsigned short* V2lT = (unsigned short*)p; p += (size_t)C * M * 2;
    float* rsum  = (float*)p;             p += (size_t)N * 4;
    float* meanw = (float*)p;             p += (size_t)N * C * 4;   // 8 MB
    float* stdw  = (float*)p;             p += (size_t)N * C * 4;   // 8 MB
    float* mu    = (float*)p;             p += (size_t)C * 4;
    float* rstd  = (float*)p;             p += (size_t)C * 4;

    for (int b = 0; b < BATCH; ++b) {
        const size_t fo = (size_t)b * C * N;
        linear_hilo_kernel<<<dim3(N / 32, C / 64), 256, 0, stream>>>(ckey + fo, Wf, bf, Fh, Fl);
        linear_hilo_kernel<<<dim3(M / 32, C / 64), 256, 0, stream>>>(skey + fo, Wg, bg, Gh, Gl);
        linear_vT_kernel<<<dim3(M / 64, C / 32), 256, 0, stream>>>(style + fo, Wh, bh, VhT, V2hT, V2lT);
        logits_mfma_kernel<<<dim3(M / 128, N / 128), 256, 0, stream>>>(Fh, Fl, Gh, Gl, S);
        rowstat_p_kernel<<<dim3(N), 256, 0, stream>>>(S, P, rsum);
        apply_mfma_kernel<<<dim3(C / 64, N / 128), 256, 0, stream>>>(P, VhT, V2hT, V2lT, rsum, meanw, stdw);
        mvn_kernel<<<dim3(C), 256, 0, stream>>>(content + fo, mu, rstd);
        final_kernel<<<dim3(N / 32, C / 32), 256, 0, stream>>>(content + fo, meanw, stdw, mu, rstd, out + fo);
    }
}

// Round 3
// 1196.664 us; speedup vs baseline: 3.0306x; 1.4263x over previous
//
#include <hip/hip_runtime.h>
#include <math.h>

#define BATCH 4
#define C 512
#define N 4096   // content spatial (64*64)
#define M 4096   // style spatial (64*64)

typedef __attribute__((ext_vector_type(8))) short short8;
typedef __attribute__((ext_vector_type(8))) __bf16 bf16x8;
typedef __attribute__((ext_vector_type(4))) float f32x4;

static __device__ __forceinline__ unsigned short f2bf(float x) {
    unsigned u = __float_as_uint(x);
    u += 0x7fff + ((u >> 16) & 1);          // round-to-nearest-even
    return (unsigned short)(u >> 16);
}
static __device__ __forceinline__ float bf2f(unsigned short h) {
    return __uint_as_float(((unsigned)h) << 16);
}
static __device__ __forceinline__ f32x4 mfma_bf16(short8 a, short8 b, f32x4 c) {
    return __builtin_amdgcn_mfma_f32_16x16x32_bf16(
        __builtin_bit_cast(bf16x8, a), __builtin_bit_cast(bf16x8, b), c, 0, 0, 0);
}

// ---------------------------------------------------------------------------
// K0: split W (512x512 fp32) into bf16 hi/lo, once per call
// ---------------------------------------------------------------------------
__global__ __launch_bounds__(256) void wsplit_kernel(
    const float* __restrict__ W, unsigned short* __restrict__ hi,
    unsigned short* __restrict__ lo)
{
    int i = blockIdx.x * 256 + threadIdx.x;
    float v = W[i];
    unsigned short h = f2bf(v);
    hi[i] = h;
    lo[i] = f2bf(v - bf2f(h));
}

// ---------------------------------------------------------------------------
// K1a: MFMA linear for Fq/Gt: out[n][o] (hi/lo bf16), o fastest.
// A = input pixels (fp32 staged, hi/lo split in-register), B = W hi/lo.
// block 64n x 64o, BK=32, waves 2x2 (wave tile 32n x 32o)
// ---------------------------------------------------------------------------
__global__ __launch_bounds__(256) void linear_fg_mfma(
    const float* __restrict__ in,                     // [C][N] batch slice
    const unsigned short* __restrict__ Whi, const unsigned short* __restrict__ Wlo,
    const float* __restrict__ bias,
    unsigned short* __restrict__ out_hi, unsigned short* __restrict__ out_lo)
{
    __shared__ float in_s[32][68];                    // [k][n] fp32
    __shared__ __align__(16) unsigned short wh_s[64][40];  // [o][k]
    __shared__ __align__(16) unsigned short wl_s[64][40];
    const int tid = threadIdx.x;
    const int n0 = blockIdx.x * 64, o0 = blockIdx.y * 64;
    const int w = tid >> 6, lane = tid & 63;
    const int wrow = w >> 1, wcol = w & 1;            // wrow: n-dir, wcol: o-dir
    const int lr = lane & 15, q = lane >> 4;
    f32x4 acc[2][2];
    #pragma unroll
    for (int i = 0; i < 2; ++i)
        #pragma unroll
        for (int j = 0; j < 2; ++j) acc[i][j] = (f32x4){0.f, 0.f, 0.f, 0.f};

    for (int kc = 0; kc < C; kc += 32) {
        __syncthreads();
        #pragma unroll
        for (int it = 0; it < 2; ++it) {
            int idx = tid + it * 256;
            int k = idx >> 4, seg = idx & 15;
            *(float4*)&in_s[k][seg * 4] =
                *(const float4*)&in[(size_t)(kc + k) * N + n0 + seg * 4];
        }
        {
            int o = tid >> 2, sg = tid & 3;
            *(float4*)&wh_s[o][sg * 8] = *(const float4*)&Whi[(size_t)(o0 + o) * 512 + kc + sg * 8];
            *(float4*)&wl_s[o][sg * 8] = *(const float4*)&Wlo[(size_t)(o0 + o) * 512 + kc + sg * 8];
        }
        __syncthreads();
        short8 ah[2], al[2], bh[2], bl[2];
        #pragma unroll
        for (int i = 0; i < 2; ++i) {
            int n = wrow * 32 + i * 16 + lr;
            #pragma unroll
            for (int j = 0; j < 8; ++j) {
                float f = in_s[q * 8 + j][n];
                unsigned short h = f2bf(f);
                ah[i][j] = (short)h;
                al[i][j] = (short)f2bf(f - bf2f(h));
            }
        }
        #pragma unroll
        for (int j = 0; j < 2; ++j) {
            int o = wcol * 32 + j * 16 + lr;
            bh[j] = *(const short8*)&wh_s[o][q * 8];
            bl[j] = *(const short8*)&wl_s[o][q * 8];
        }
        #pragma unroll
        for (int i = 0; i < 2; ++i)
            #pragma unroll
            for (int j = 0; j < 2; ++j) {
                acc[i][j] = mfma_bf16(ah[i], bh[j], acc[i][j]);
                acc[i][j] = mfma_bf16(ah[i], bl[j], acc[i][j]);
                acc[i][j] = mfma_bf16(al[i], bh[j], acc[i][j]);
            }
    }
    #pragma unroll
    for (int i = 0; i < 2; ++i)
        #pragma unroll
        for (int j = 0; j < 2; ++j) {
            int o = o0 + wcol * 32 + j * 16 + lr;
            float bo = bias[o];
            #pragma unroll
            for (int r = 0; r < 4; ++r) {
                int n = n0 + wrow * 32 + i * 16 + q * 4 + r;
                float v = acc[i][j][r] + bo;
                unsigned short h = f2bf(v);
                out_hi[(size_t)n * 512 + o] = h;
                out_lo[(size_t)n * 512 + o] = f2bf(v - bf2f(h));
            }
        }
}

// ---------------------------------------------------------------------------
// K1b: MFMA linear for V: vhT[o][m], v2hT/v2lT = hi/lo of vh^2. Transposed
// output falls out of C/D layout (rows=o from A=W, cols=m from B=input).
// ---------------------------------------------------------------------------
__global__ __launch_bounds__(256) void linear_v_mfma(
    const float* __restrict__ in,                     // [C][M] batch slice
    const unsigned short* __restrict__ Whi, const unsigned short* __restrict__ Wlo,
    const float* __restrict__ bias,
    unsigned short* __restrict__ vhT, unsigned short* __restrict__ v2hT,
    unsigned short* __restrict__ v2lT)
{
    __shared__ float in_s[32][68];                    // [k][m]
    __shared__ __align__(16) unsigned short wh_s[64][40];
    __shared__ __align__(16) unsigned short wl_s[64][40];
    const int tid = threadIdx.x;
    const int m0 = blockIdx.x * 64, o0 = blockIdx.y * 64;
    const int w = tid >> 6, lane = tid & 63;
    const int wrow = w >> 1, wcol = w & 1;            // wrow: o-dir, wcol: m-dir
    const int lr = lane & 15, q = lane >> 4;
    f32x4 acc[2][2];
    #pragma unroll
    for (int i = 0; i < 2; ++i)
        #pragma unroll
        for (int j = 0; j < 2; ++j) acc[i][j] = (f32x4){0.f, 0.f, 0.f, 0.f};

    for (int kc = 0; kc < C; kc += 32) {
        __syncthreads();
        #pragma unroll
        for (int it = 0; it < 2; ++it) {
            int idx = tid + it * 256;
            int k = idx >> 4, seg = idx & 15;
            *(float4*)&in_s[k][seg * 4] =
                *(const float4*)&in[(size_t)(kc + k) * N + m0 + seg * 4];
        }
        {
            int o = tid >> 2, sg = tid & 3;
            *(float4*)&wh_s[o][sg * 8] = *(const float4*)&Whi[(size_t)(o0 + o) * 512 + kc + sg * 8];
            *(float4*)&wl_s[o][sg * 8] = *(const float4*)&Wlo[(size_t)(o0 + o) * 512 + kc + sg * 8];
        }
        __syncthreads();
        short8 ah[2], al[2], bh[2], bl[2];
        #pragma unroll
        for (int i = 0; i < 2; ++i) {
            int o = wrow * 32 + i * 16 + lr;
            ah[i] = *(const short8*)&wh_s[o][q * 8];
            al[i] = *(const short8*)&wl_s[o][q * 8];
        }
        #pragma unroll
        for (int j = 0; j < 2; ++j) {
            int m = wcol * 32 + j * 16 + lr;
            #pragma unroll
            for (int t = 0; t < 8; ++t) {
                float f = in_s[q * 8 + t][m];
                unsigned short h = f2bf(f);
                bh[j][t] = (short)h;
                bl[j][t] = (short)f2bf(f - bf2f(h));
            }
        }
        #pragma unroll
        for (int i = 0; i < 2; ++i)
            #pragma unroll
            for (int j = 0; j < 2; ++j) {
                acc[i][j] = mfma_bf16(ah[i], bh[j], acc[i][j]);
                acc[i][j] = mfma_bf16(ah[i], bl[j], acc[i][j]);
                acc[i][j] = mfma_bf16(al[i], bh[j], acc[i][j]);
            }
    }
    #pragma unroll
    for (int i = 0; i < 2; ++i)
        #pragma unroll
        for (int r = 0; r < 4; ++r) {
            int o = o0 + wrow * 32 + i * 16 + q * 4 + r;
            float bo = bias[o];
            #pragma unroll
            for (int j = 0; j < 2; ++j) {
                int m = m0 + wcol * 32 + j * 16 + lr;
                float v = acc[i][j][r] + bo;
                unsigned short vh = f2bf(v);
                float vhf = bf2f(vh);
                float vsq = vhf * vhf;
                unsigned short v2h = f2bf(vsq);
                unsigned short v2l = f2bf(vsq - bf2f(v2h));
                size_t off = (size_t)o * M + m;
                vhT[off] = vh;
                v2hT[off] = v2h;
                v2lT[off] = v2l;
            }
        }
}

// ---------------------------------------------------------------------------
// K2: logits MFMA: S[n][m] = Ah.BhT + Ah.BlT + Al.BhT  (hi/lo bf16 split)
// block tile 128n x 128m, BK=32, 4 waves (2x2), wave tile 64x64
// ---------------------------------------------------------------------------
__global__ __launch_bounds__(256) void logits_mfma_kernel(
    const unsigned short* __restrict__ Ah, const unsigned short* __restrict__ Al,
    const unsigned short* __restrict__ Bh, const unsigned short* __restrict__ Bl,
    float* __restrict__ S)
{
    __shared__ __align__(16) unsigned short Ah_s[128 * 40];
    __shared__ __align__(16) unsigned short Al_s[128 * 40];
    __shared__ __align__(16) unsigned short Bh_s[128 * 40];
    __shared__ __align__(16) unsigned short Bl_s[128 * 40];
    const int tid = threadIdx.x;
    const int n0 = blockIdx.y * 128, m0 = blockIdx.x * 128;
    const int w = tid >> 6, lane = tid & 63;
    const int wrow = w >> 1, wcol = w & 1;
    const int lr = lane & 15, q = lane >> 4;
    f32x4 acc[4][4];
    #pragma unroll
    for (int i = 0; i < 4; ++i)
        #pragma unroll
        for (int j = 0; j < 4; ++j)
            acc[i][j] = (f32x4){0.f, 0.f, 0.f, 0.f};

    for (int kc = 0; kc < C; kc += 32) {
        __syncthreads();
        #pragma unroll
        for (int it = 0; it < 2; ++it) {
            int idx = tid + it * 256;
            int row = idx >> 2, seg = idx & 3;
            int ldso = row * 40 + seg * 8;
            int go = kc + seg * 8;
            *(float4*)&Ah_s[ldso] = *(const float4*)&Ah[(size_t)(n0 + row) * C + go];
            *(float4*)&Al_s[ldso] = *(const float4*)&Al[(size_t)(n0 + row) * C + go];
            *(float4*)&Bh_s[ldso] = *(const float4*)&Bh[(size_t)(m0 + row) * C + go];
            *(float4*)&Bl_s[ldso] = *(const float4*)&Bl[(size_t)(m0 + row) * C + go];
        }
        __syncthreads();
        short8 ah[4], al[4], bh[4], bl[4];
        #pragma unroll
        for (int i = 0; i < 4; ++i) {
            int ro = (wrow * 64 + i * 16 + lr) * 40 + q * 8;
            int co = (wcol * 64 + i * 16 + lr) * 40 + q * 8;
            ah[i] = *(const short8*)&Ah_s[ro];
            al[i] = *(const short8*)&Al_s[ro];
            bh[i] = *(const short8*)&Bh_s[co];
            bl[i] = *(const short8*)&Bl_s[co];
        }
        #pragma unroll
        for (int i = 0; i < 4; ++i)
            #pragma unroll
            for (int j = 0; j < 4; ++j) {
                acc[i][j] = mfma_bf16(ah[i], bh[j], acc[i][j]);
                acc[i][j] = mfma_bf16(ah[i], bl[j], acc[i][j]);
                acc[i][j] = mfma_bf16(al[i], bh[j], acc[i][j]);
            }
    }
    #pragma unroll
    for (int i = 0; i < 4; ++i) {
        int nb = n0 + wrow * 64 + i * 16 + q * 4;
        #pragma unroll
        for (int j = 0; j < 4; ++j) {
            int m = m0 + wcol * 64 + j * 16 + lr;
            #pragma unroll
            for (int r = 0; r < 4; ++r)
                S[(size_t)(nb + r) * M + m] = acc[i][j][r];
        }
    }
}

// ---------------------------------------------------------------------------
// K3: row softmax -> bf16 P, rsum = sum of the ROUNDED p (consistency!)
// ---------------------------------------------------------------------------
__global__ __launch_bounds__(256) void rowstat_p_kernel(
    const float* __restrict__ S, unsigned short* __restrict__ P,
    float* __restrict__ rsum)
{
    const int n = blockIdx.x;
    const int tid = threadIdx.x;
    const float* row = S + (size_t)n * M;
    float v[16];
    #pragma unroll
    for (int i = 0; i < 16; ++i) v[i] = row[tid + i * 256];
    float lm = -INFINITY;
    #pragma unroll
    for (int i = 0; i < 16; ++i) lm = fmaxf(lm, v[i]);
    #pragma unroll
    for (int off = 32; off > 0; off >>= 1) lm = fmaxf(lm, __shfl_xor(lm, off, 64));
    __shared__ float red[4];
    __shared__ float redsum[4];
    const int wid = tid >> 6, lane = tid & 63;
    if (lane == 0) red[wid] = lm;
    __syncthreads();
    const float rm = fmaxf(fmaxf(red[0], red[1]), fmaxf(red[2], red[3]));
    float ls = 0.f;
    unsigned short* prow = P + (size_t)n * M;
    #pragma unroll
    for (int i = 0; i < 16; ++i) {
        float p = __expf(v[i] - rm);
        unsigned short pb = f2bf(p);
        prow[tid + i * 256] = pb;
        ls += bf2f(pb);
    }
    #pragma unroll
    for (int off = 32; off > 0; off >>= 1) ls += __shfl_xor(ls, off, 64);
    if (lane == 0) redsum[wid] = ls;
    __syncthreads();
    if (tid == 0) rsum[n] = redsum[0] + redsum[1] + redsum[2] + redsum[3];
}

// ---------------------------------------------------------------------------
// K4: apply MFMA (BATCHED over blockIdx.z): accm = P@vh, acc2 = P@(v2h+v2l)
// block tile 128n x 64c, BK=32, waves 2x2, wave tile 64n x 32c
// ---------------------------------------------------------------------------
__global__ __launch_bounds__(256) void apply_mfma_kernel(
    const unsigned short* __restrict__ P, const unsigned short* __restrict__ VhT,
    const unsigned short* __restrict__ V2hT, const unsigned short* __restrict__ V2lT,
    const float* __restrict__ rsum,
    float* __restrict__ meanw, float* __restrict__ stdw)
{
    const int b = blockIdx.z;
    P    += (size_t)b * N * M;
    VhT  += (size_t)b * C * M;
    V2hT += (size_t)b * C * M;
    V2lT += (size_t)b * C * M;
    rsum += (size_t)b * N;
    meanw += (size_t)b * N * C;
    stdw  += (size_t)b * N * C;

    __shared__ __align__(16) unsigned short P_s[128 * 40];
    __shared__ __align__(16) unsigned short Vh_s[64 * 40];
    __shared__ __align__(16) unsigned short V2h_s[64 * 40];
    __shared__ __align__(16) unsigned short V2l_s[64 * 40];
    const int tid = threadIdx.x;
    const int c0 = blockIdx.x * 64, n0 = blockIdx.y * 128;
    const int w = tid >> 6, lane = tid & 63;
    const int wrow = w >> 1, wcol = w & 1;
    const int lr = lane & 15, q = lane >> 4;
    f32x4 accm[4][2], acc2[4][2];
    #pragma unroll
    for (int i = 0; i < 4; ++i)
        #pragma unroll
        for (int j = 0; j < 2; ++j) {
            accm[i][j] = (f32x4){0.f, 0.f, 0.f, 0.f};
            acc2[i][j] = (f32x4){0.f, 0.f, 0.f, 0.f};
        }

    for (int mc = 0; mc < M; mc += 32) {
        __syncthreads();
        #pragma unroll
        for (int it = 0; it < 2; ++it) {
            int idx = tid + it * 256;
            int row = idx >> 2, seg = idx & 3;
            *(float4*)&P_s[row * 40 + seg * 8] =
                *(const float4*)&P[(size_t)(n0 + row) * M + mc + seg * 8];
        }
        {
            int row = tid >> 2, seg = tid & 3;
            int ldso = row * 40 + seg * 8;
            size_t go = (size_t)(c0 + row) * M + mc + seg * 8;
            *(float4*)&Vh_s[ldso]  = *(const float4*)&VhT[go];
            *(float4*)&V2h_s[ldso] = *(const float4*)&V2hT[go];
            *(float4*)&V2l_s[ldso] = *(const float4*)&V2lT[go];
        }
        __syncthreads();
        short8 a[4], bmat[2], b2h[2], b2l[2];
        #pragma unroll
        for (int i = 0; i < 4; ++i)
            a[i] = *(const short8*)&P_s[(wrow * 64 + i * 16 + lr) * 40 + q * 8];
        #pragma unroll
        for (int j = 0; j < 2; ++j) {
            int co = (wcol * 32 + j * 16 + lr) * 40 + q * 8;
            bmat[j] = *(const short8*)&Vh_s[co];
            b2h[j]  = *(const short8*)&V2h_s[co];
            b2l[j]  = *(const short8*)&V2l_s[co];
        }
        #pragma unroll
        for (int i = 0; i < 4; ++i)
            #pragma unroll
            for (int j = 0; j < 2; ++j) {
                accm[i][j] = mfma_bf16(a[i], bmat[j], accm[i][j]);
                acc2[i][j] = mfma_bf16(a[i], b2h[j],  acc2[i][j]);
                acc2[i][j] = mfma_bf16(a[i], b2l[j],  acc2[i][j]);
            }
    }
    #pragma unroll
    for (int i = 0; i < 4; ++i) {
        int nb = n0 + wrow * 64 + i * 16 + q * 4;
        #pragma unroll
        for (int j = 0; j < 2; ++j) {
            int c = c0 + wcol * 32 + j * 16 + lr;
            #pragma unroll
            for (int r = 0; r < 4; ++r) {
                int n = nb + r;
                float inv = 1.0f / rsum[n];
                float mn = accm[i][j][r] * inv;
                float m2 = acc2[i][j][r] * inv;
                float sd = sqrtf(fmaxf(m2 - mn * mn, 0.f));
                meanw[(size_t)n * C + c] = mn;
                stdw[(size_t)n * C + c]  = sd;
            }
        }
    }
}

// ---------------------------------------------------------------------------
// K5: instance-norm stats per channel (fp32), batched over blockIdx.y
// ---------------------------------------------------------------------------
__global__ __launch_bounds__(256) void mvn_kernel(
    const float* __restrict__ content, float* __restrict__ mu, float* __restrict__ rstd)
{
    const int b = blockIdx.y;
    content += (size_t)b * C * N;
    mu   += (size_t)b * C;
    rstd += (size_t)b * C;
    const int c = blockIdx.x;
    const int tid = threadIdx.x;
    const float* row = content + (size_t)c * N;
    float s = 0.f, ss = 0.f;
    for (int i = tid; i < N; i += 256) {
        float v = row[i];
        s += v;
        ss = fmaf(v, v, ss);
    }
    #pragma unroll
    for (int off = 32; off > 0; off >>= 1) {
        s  += __shfl_xor(s,  off, 64);
        ss += __shfl_xor(ss, off, 64);
    }
    __shared__ float rs[4], rss[4];
    const int wid = tid >> 6, lane = tid & 63;
    if (lane == 0) { rs[wid] = s; rss[wid] = ss; }
    __syncthreads();
    if (tid == 0) {
        float st = rs[0] + rs[1] + rs[2] + rs[3];
        float sst = rss[0] + rss[1] + rss[2] + rss[3];
        float m = st / (float)N;
        float var = (sst - st * st / (float)N) / (float)(N - 1);
        mu[c] = m;
        rstd[c] = rsqrtf(var + 1e-5f);
    }
}

// ---------------------------------------------------------------------------
// K6: final combine (fp32), batched over blockIdx.z
// ---------------------------------------------------------------------------
__global__ __launch_bounds__(256) void final_kernel(
    const float* __restrict__ content, const float* __restrict__ meanw,
    const float* __restrict__ stdw, const float* __restrict__ mu,
    const float* __restrict__ rstd, float* __restrict__ out)
{
    const int b = blockIdx.z;
    content += (size_t)b * C * N;
    out     += (size_t)b * C * N;
    meanw   += (size_t)b * N * C;
    stdw    += (size_t)b * N * C;
    mu   += (size_t)b * C;
    rstd += (size_t)b * C;

    __shared__ float mn_s[32][33], sd_s[32][33];
    const int tid = threadIdx.x;
    const int n0 = blockIdx.x * 32;
    const int c0 = blockIdx.y * 32;
    const int tx = tid & 31, ty = tid >> 5;
    #pragma unroll
    for (int i = 0; i < 4; ++i) {
        int n = ty + i * 8;
        mn_s[tx][n] = meanw[(size_t)(n0 + n) * C + c0 + tx];
        sd_s[tx][n] = stdw [(size_t)(n0 + n) * C + c0 + tx];
    }
    __syncthreads();
    #pragma unroll
    for (int i = 0; i < 4; ++i) {
        int c = ty + i * 8;
        float m = mu[c0 + c], r = rstd[c0 + c];
        size_t off = (size_t)(c0 + c) * N + n0 + tx;
        float x = content[off];
        out[off] = sd_s[c][tx] * (x - m) * r + mn_s[c][tx];
    }
}

// ---------------------------------------------------------------------------
extern "C" void kernel_launch(void* const* d_in, const int* in_sizes, int n_in,
                              void* d_out, int out_size, void* d_ws, size_t ws_size,
                              hipStream_t stream)
{
    const float* content = (const float*)d_in[0];
    const float* style   = (const float*)d_in[1];
    const float* ckey    = (const float*)d_in[2];
    const float* skey    = (const float*)d_in[3];
    const float* Wf      = (const float*)d_in[4];
    const float* bf      = (const float*)d_in[5];
    const float* Wg      = (const float*)d_in[6];
    const float* bg      = (const float*)d_in[7];
    const float* Wh      = (const float*)d_in[8];
    const float* bh      = (const float*)d_in[9];
    float* out = (float*)d_out;

    // ---- workspace sizing: batched path if ws allows, else per-batch ----
    const size_t sz_w  = (size_t)512 * 512 * 2;      // one W half
    const size_t sz_S  = (size_t)N * M * 4;
    const size_t sz_FG = (size_t)N * C * 2;          // one of Fh/Fl/Gh/Gl
    const size_t sz_P1 = (size_t)N * M * 2;
    const size_t sz_V1 = (size_t)C * M * 2;
    const size_t sz_r1 = (size_t)N * 4;
    const size_t sz_m1 = (size_t)N * C * 4;
    const size_t sz_u1 = (size_t)C * 4;
    auto need = [&](size_t nb) {
        return 6 * sz_w + sz_S + 4 * sz_FG +
               nb * (sz_P1 + 3 * sz_V1 + sz_r1 + 2 * sz_m1 + 2 * sz_u1) + (size_t)64 * 1024;
    };
    const bool batched = ws_size >= need(BATCH);
    const size_t NB = batched ? BATCH : 1;

    char* p = (char*)d_ws;
    auto alloc = [&](size_t bytes) {
        char* r = p;
        p += (bytes + 255) & ~(size_t)255;
        return r;
    };
    unsigned short* WfH = (unsigned short*)alloc(sz_w);
    unsigned short* WfL = (unsigned short*)alloc(sz_w);
    unsigned short* WgH = (unsigned short*)alloc(sz_w);
    unsigned short* WgL = (unsigned short*)alloc(sz_w);
    unsigned short* WhH = (unsigned short*)alloc(sz_w);
    unsigned short* WhL = (unsigned short*)alloc(sz_w);
    float* S = (float*)alloc(sz_S);
    unsigned short* Fh = (unsigned short*)alloc(sz_FG);
    unsigned short* Fl = (unsigned short*)alloc(sz_FG);
    unsigned short* Gh = (unsigned short*)alloc(sz_FG);
    unsigned short* Gl = (unsigned short*)alloc(sz_FG);
    unsigned short* P    = (unsigned short*)alloc(NB * sz_P1);
    unsigned short* VhT  = (unsigned short*)alloc(NB * sz_V1);
    unsigned short* V2hT = (unsigned short*)alloc(NB * sz_V1);
    unsigned short* V2lT = (unsigned short*)alloc(NB * sz_V1);
    float* rsum  = (float*)alloc(NB * sz_r1);
    float* meanw = (float*)alloc(NB * sz_m1);
    float* stdw  = (float*)alloc(NB * sz_m1);
    float* mu    = (float*)alloc(NB * sz_u1);
    float* rstd  = (float*)alloc(NB * sz_u1);

    // split weights once per call
    wsplit_kernel<<<dim3(1024), 256, 0, stream>>>(Wf, WfH, WfL);
    wsplit_kernel<<<dim3(1024), 256, 0, stream>>>(Wg, WgH, WgL);
    wsplit_kernel<<<dim3(1024), 256, 0, stream>>>(Wh, WhH, WhL);

    for (int b = 0; b < BATCH; ++b) {
        const size_t fo = (size_t)b * C * N;
        const size_t bi = batched ? (size_t)b : 0;
        linear_fg_mfma<<<dim3(N / 64, C / 64), 256, 0, stream>>>(ckey + fo, WfH, WfL, bf, Fh, Fl);
        linear_fg_mfma<<<dim3(M / 64, C / 64), 256, 0, stream>>>(skey + fo, WgH, WgL, bg, Gh, Gl);
        linear_v_mfma<<<dim3(M / 64, C / 64), 256, 0, stream>>>(style + fo, WhH, WhL, bh,
                                                                VhT + bi * C * M,
                                                                V2hT + bi * C * M,
                                                                V2lT + bi * C * M);
        logits_mfma_kernel<<<dim3(M / 128, N / 128), 256, 0, stream>>>(Fh, Fl, Gh, Gl, S);
        rowstat_p_kernel<<<dim3(N), 256, 0, stream>>>(S, P + bi * (size_t)N * M, rsum + bi * N);
        if (!batched) {
            apply_mfma_kernel<<<dim3(C / 64, N / 128, 1), 256, 0, stream>>>(
                P, VhT, V2hT, V2lT, rsum, meanw, stdw);
            mvn_kernel<<<dim3(C, 1), 256, 0, stream>>>(content + fo, mu, rstd);
            final_kernel<<<dim3(N / 32, C / 32, 1), 256, 0, stream>>>(
                content + fo, meanw, stdw, mu, rstd, out + fo);
        }
    }
    if (batched) {
        apply_mfma_kernel<<<dim3(C / 64, N / 128, BATCH), 256, 0, stream>>>(
            P, VhT, V2hT, V2lT, rsum, meanw, stdw);
        mvn_kernel<<<dim3(C, BATCH), 256, 0, stream>>>(content, mu, rstd);
        final_kernel<<<dim3(N / 32, C / 32, BATCH), 256, 0, stream>>>(
            content, meanw, stdw, mu, rstd, out);
    }
}

// Round 4
// 1147.868 us; speedup vs baseline: 3.1595x; 1.0425x over previous
//
#include <hip/hip_runtime.h>
#include <math.h>

#define BATCH 4
#define C 512
#define N 4096   // content spatial (64*64)
#define M 4096   // style spatial (64*64)
#define MSPLIT 4

typedef __attribute__((ext_vector_type(8))) short short8;
typedef __attribute__((ext_vector_type(8))) __bf16 bf16x8;
typedef __attribute__((ext_vector_type(4))) float f32x4;

static __device__ __forceinline__ unsigned short f2bf(float x) {
    unsigned u = __float_as_uint(x);
    u += 0x7fff + ((u >> 16) & 1);          // round-to-nearest-even
    return (unsigned short)(u >> 16);
}
static __device__ __forceinline__ float bf2f(unsigned short h) {
    return __uint_as_float(((unsigned)h) << 16);
}
static __device__ __forceinline__ f32x4 mfma_bf16(short8 a, short8 b, f32x4 c) {
    return __builtin_amdgcn_mfma_f32_16x16x32_bf16(
        __builtin_bit_cast(bf16x8, a), __builtin_bit_cast(bf16x8, b), c, 0, 0, 0);
}

// ---------------------------------------------------------------------------
// K0: split W (512x512 fp32) into bf16 hi/lo, once per call
// ---------------------------------------------------------------------------
__global__ __launch_bounds__(256) void wsplit_kernel(
    const float* __restrict__ W, unsigned short* __restrict__ hi,
    unsigned short* __restrict__ lo)
{
    int i = blockIdx.x * 256 + threadIdx.x;
    float v = W[i];
    unsigned short h = f2bf(v);
    hi[i] = h;
    lo[i] = f2bf(v - bf2f(h));
}

// ---------------------------------------------------------------------------
// K1a: MFMA linear for Fq/Gt: out[n][o] (hi/lo bf16), o fastest.
// block 64n x 64o, BK=32, waves 2x2 (wave tile 32n x 32o)
// ---------------------------------------------------------------------------
__global__ __launch_bounds__(256) void linear_fg_mfma(
    const float* __restrict__ in,                     // [C][N] batch slice
    const unsigned short* __restrict__ Whi, const unsigned short* __restrict__ Wlo,
    const float* __restrict__ bias,
    unsigned short* __restrict__ out_hi, unsigned short* __restrict__ out_lo)
{
    __shared__ float in_s[32][68];                    // [k][n] fp32
    __shared__ __align__(16) unsigned short wh_s[64][40];  // [o][k]
    __shared__ __align__(16) unsigned short wl_s[64][40];
    const int tid = threadIdx.x;
    const int n0 = blockIdx.x * 64, o0 = blockIdx.y * 64;
    const int w = tid >> 6, lane = tid & 63;
    const int wrow = w >> 1, wcol = w & 1;
    const int lr = lane & 15, q = lane >> 4;
    f32x4 acc[2][2];
    #pragma unroll
    for (int i = 0; i < 2; ++i)
        #pragma unroll
        for (int j = 0; j < 2; ++j) acc[i][j] = (f32x4){0.f, 0.f, 0.f, 0.f};

    for (int kc = 0; kc < C; kc += 32) {
        __syncthreads();
        #pragma unroll
        for (int it = 0; it < 2; ++it) {
            int idx = tid + it * 256;
            int k = idx >> 4, seg = idx & 15;
            *(float4*)&in_s[k][seg * 4] =
                *(const float4*)&in[(size_t)(kc + k) * N + n0 + seg * 4];
        }
        {
            int o = tid >> 2, sg = tid & 3;
            *(float4*)&wh_s[o][sg * 8] = *(const float4*)&Whi[(size_t)(o0 + o) * 512 + kc + sg * 8];
            *(float4*)&wl_s[o][sg * 8] = *(const float4*)&Wlo[(size_t)(o0 + o) * 512 + kc + sg * 8];
        }
        __syncthreads();
        short8 ah[2], al[2], bh[2], bl[2];
        #pragma unroll
        for (int i = 0; i < 2; ++i) {
            int n = wrow * 32 + i * 16 + lr;
            #pragma unroll
            for (int j = 0; j < 8; ++j) {
                float f = in_s[q * 8 + j][n];
                unsigned short h = f2bf(f);
                ah[i][j] = (short)h;
                al[i][j] = (short)f2bf(f - bf2f(h));
            }
        }
        #pragma unroll
        for (int j = 0; j < 2; ++j) {
            int o = wcol * 32 + j * 16 + lr;
            bh[j] = *(const short8*)&wh_s[o][q * 8];
            bl[j] = *(const short8*)&wl_s[o][q * 8];
        }
        #pragma unroll
        for (int i = 0; i < 2; ++i)
            #pragma unroll
            for (int j = 0; j < 2; ++j) {
                acc[i][j] = mfma_bf16(ah[i], bh[j], acc[i][j]);
                acc[i][j] = mfma_bf16(ah[i], bl[j], acc[i][j]);
                acc[i][j] = mfma_bf16(al[i], bh[j], acc[i][j]);
            }
    }
    #pragma unroll
    for (int i = 0; i < 2; ++i)
        #pragma unroll
        for (int j = 0; j < 2; ++j) {
            int o = o0 + wcol * 32 + j * 16 + lr;
            float bo = bias[o];
            #pragma unroll
            for (int r = 0; r < 4; ++r) {
                int n = n0 + wrow * 32 + i * 16 + q * 4 + r;
                float v = acc[i][j][r] + bo;
                unsigned short h = f2bf(v);
                out_hi[(size_t)n * 512 + o] = h;
                out_lo[(size_t)n * 512 + o] = f2bf(v - bf2f(h));
            }
        }
}

// ---------------------------------------------------------------------------
// K1b: MFMA linear for V: vhT[o][m], v2hT/v2lT = hi/lo of vh^2 (transposed
// output falls out of C/D layout: rows=o from A=W, cols=m from B=input)
// ---------------------------------------------------------------------------
__global__ __launch_bounds__(256) void linear_v_mfma(
    const float* __restrict__ in,                     // [C][M] batch slice
    const unsigned short* __restrict__ Whi, const unsigned short* __restrict__ Wlo,
    const float* __restrict__ bias,
    unsigned short* __restrict__ vhT, unsigned short* __restrict__ v2hT,
    unsigned short* __restrict__ v2lT)
{
    __shared__ float in_s[32][68];                    // [k][m]
    __shared__ __align__(16) unsigned short wh_s[64][40];
    __shared__ __align__(16) unsigned short wl_s[64][40];
    const int tid = threadIdx.x;
    const int m0 = blockIdx.x * 64, o0 = blockIdx.y * 64;
    const int w = tid >> 6, lane = tid & 63;
    const int wrow = w >> 1, wcol = w & 1;
    const int lr = lane & 15, q = lane >> 4;
    f32x4 acc[2][2];
    #pragma unroll
    for (int i = 0; i < 2; ++i)
        #pragma unroll
        for (int j = 0; j < 2; ++j) acc[i][j] = (f32x4){0.f, 0.f, 0.f, 0.f};

    for (int kc = 0; kc < C; kc += 32) {
        __syncthreads();
        #pragma unroll
        for (int it = 0; it < 2; ++it) {
            int idx = tid + it * 256;
            int k = idx >> 4, seg = idx & 15;
            *(float4*)&in_s[k][seg * 4] =
                *(const float4*)&in[(size_t)(kc + k) * N + m0 + seg * 4];
        }
        {
            int o = tid >> 2, sg = tid & 3;
            *(float4*)&wh_s[o][sg * 8] = *(const float4*)&Whi[(size_t)(o0 + o) * 512 + kc + sg * 8];
            *(float4*)&wl_s[o][sg * 8] = *(const float4*)&Wlo[(size_t)(o0 + o) * 512 + kc + sg * 8];
        }
        __syncthreads();
        short8 ah[2], al[2], bh[2], bl[2];
        #pragma unroll
        for (int i = 0; i < 2; ++i) {
            int o = wrow * 32 + i * 16 + lr;
            ah[i] = *(const short8*)&wh_s[o][q * 8];
            al[i] = *(const short8*)&wl_s[o][q * 8];
        }
        #pragma unroll
        for (int j = 0; j < 2; ++j) {
            int m = wcol * 32 + j * 16 + lr;
            #pragma unroll
            for (int t = 0; t < 8; ++t) {
                float f = in_s[q * 8 + t][m];
                unsigned short h = f2bf(f);
                bh[j][t] = (short)h;
                bl[j][t] = (short)f2bf(f - bf2f(h));
            }
        }
        #pragma unroll
        for (int i = 0; i < 2; ++i)
            #pragma unroll
            for (int j = 0; j < 2; ++j) {
                acc[i][j] = mfma_bf16(ah[i], bh[j], acc[i][j]);
                acc[i][j] = mfma_bf16(ah[i], bl[j], acc[i][j]);
                acc[i][j] = mfma_bf16(al[i], bh[j], acc[i][j]);
            }
    }
    #pragma unroll
    for (int i = 0; i < 2; ++i)
        #pragma unroll
        for (int r = 0; r < 4; ++r) {
            int o = o0 + wrow * 32 + i * 16 + q * 4 + r;
            float bo = bias[o];
            #pragma unroll
            for (int j = 0; j < 2; ++j) {
                int m = m0 + wcol * 32 + j * 16 + lr;
                float v = acc[i][j][r] + bo;
                unsigned short vh = f2bf(v);
                float vhf = bf2f(vh);
                float vsq = vhf * vhf;
                unsigned short v2h = f2bf(vsq);
                unsigned short v2l = f2bf(vsq - bf2f(v2h));
                size_t off = (size_t)o * M + m;
                vhT[off] = vh;
                v2hT[off] = v2h;
                v2lT[off] = v2l;
            }
        }
}

// ---------------------------------------------------------------------------
// K2: logits MFMA: S[n][m] = Ah.BhT + Ah.BlT + Al.BhT  (hi/lo bf16 split)
// block tile 128n x 128m, BK=32, 4 waves (2x2), wave tile 64x64
// ---------------------------------------------------------------------------
__global__ __launch_bounds__(256) void logits_mfma_kernel(
    const unsigned short* __restrict__ Ah, const unsigned short* __restrict__ Al,
    const unsigned short* __restrict__ Bh, const unsigned short* __restrict__ Bl,
    float* __restrict__ S)
{
    __shared__ __align__(16) unsigned short Ah_s[128 * 40];
    __shared__ __align__(16) unsigned short Al_s[128 * 40];
    __shared__ __align__(16) unsigned short Bh_s[128 * 40];
    __shared__ __align__(16) unsigned short Bl_s[128 * 40];
    const int tid = threadIdx.x;
    const int n0 = blockIdx.y * 128, m0 = blockIdx.x * 128;
    const int w = tid >> 6, lane = tid & 63;
    const int wrow = w >> 1, wcol = w & 1;
    const int lr = lane & 15, q = lane >> 4;
    f32x4 acc[4][4];
    #pragma unroll
    for (int i = 0; i < 4; ++i)
        #pragma unroll
        for (int j = 0; j < 4; ++j)
            acc[i][j] = (f32x4){0.f, 0.f, 0.f, 0.f};

    for (int kc = 0; kc < C; kc += 32) {
        __syncthreads();
        #pragma unroll
        for (int it = 0; it < 2; ++it) {
            int idx = tid + it * 256;
            int row = idx >> 2, seg = idx & 3;
            int ldso = row * 40 + seg * 8;
            int go = kc + seg * 8;
            *(float4*)&Ah_s[ldso] = *(const float4*)&Ah[(size_t)(n0 + row) * C + go];
            *(float4*)&Al_s[ldso] = *(const float4*)&Al[(size_t)(n0 + row) * C + go];
            *(float4*)&Bh_s[ldso] = *(const float4*)&Bh[(size_t)(m0 + row) * C + go];
            *(float4*)&Bl_s[ldso] = *(const float4*)&Bl[(size_t)(m0 + row) * C + go];
        }
        __syncthreads();
        short8 ah[4], al[4], bh[4], bl[4];
        #pragma unroll
        for (int i = 0; i < 4; ++i) {
            int ro = (wrow * 64 + i * 16 + lr) * 40 + q * 8;
            int co = (wcol * 64 + i * 16 + lr) * 40 + q * 8;
            ah[i] = *(const short8*)&Ah_s[ro];
            al[i] = *(const short8*)&Al_s[ro];
            bh[i] = *(const short8*)&Bh_s[co];
            bl[i] = *(const short8*)&Bl_s[co];
        }
        #pragma unroll
        for (int i = 0; i < 4; ++i)
            #pragma unroll
            for (int j = 0; j < 4; ++j) {
                acc[i][j] = mfma_bf16(ah[i], bh[j], acc[i][j]);
                acc[i][j] = mfma_bf16(ah[i], bl[j], acc[i][j]);
                acc[i][j] = mfma_bf16(al[i], bh[j], acc[i][j]);
            }
    }
    #pragma unroll
    for (int i = 0; i < 4; ++i) {
        int nb = n0 + wrow * 64 + i * 16 + q * 4;
        #pragma unroll
        for (int j = 0; j < 4; ++j) {
            int m = m0 + wcol * 64 + j * 16 + lr;
            #pragma unroll
            for (int r = 0; r < 4; ++r)
                S[(size_t)(nb + r) * M + m] = acc[i][j][r];
        }
    }
}

// ---------------------------------------------------------------------------
// K3: row softmax -> bf16 P, rsum = sum of the ROUNDED p (consistency!)
// ---------------------------------------------------------------------------
__global__ __launch_bounds__(256) void rowstat_p_kernel(
    const float* __restrict__ S, unsigned short* __restrict__ P,
    float* __restrict__ rsum)
{
    const int n = blockIdx.x;
    const int tid = threadIdx.x;
    const float* row = S + (size_t)n * M;
    float v[16];
    #pragma unroll
    for (int i = 0; i < 16; ++i) v[i] = row[tid + i * 256];
    float lm = -INFINITY;
    #pragma unroll
    for (int i = 0; i < 16; ++i) lm = fmaxf(lm, v[i]);
    #pragma unroll
    for (int off = 32; off > 0; off >>= 1) lm = fmaxf(lm, __shfl_xor(lm, off, 64));
    __shared__ float red[4];
    __shared__ float redsum[4];
    const int wid = tid >> 6, lane = tid & 63;
    if (lane == 0) red[wid] = lm;
    __syncthreads();
    const float rm = fmaxf(fmaxf(red[0], red[1]), fmaxf(red[2], red[3]));
    float ls = 0.f;
    unsigned short* prow = P + (size_t)n * M;
    #pragma unroll
    for (int i = 0; i < 16; ++i) {
        float p = __expf(v[i] - rm);
        unsigned short pb = f2bf(p);
        prow[tid + i * 256] = pb;
        ls += bf2f(pb);
    }
    #pragma unroll
    for (int off = 32; off > 0; off >>= 1) ls += __shfl_xor(ls, off, 64);
    if (lane == 0) redsum[wid] = ls;
    __syncthreads();
    if (tid == 0) rsum[n] = redsum[0] + redsum[1] + redsum[2] + redsum[3];
}

// ---------------------------------------------------------------------------
// K4: apply partial (split-M): each z accumulates over M/MSPLIT columns,
// writes raw fp32 accm/acc2 partials. Grid (C/64, N/128, MSPLIT) = 1024
// blocks -> 4 blocks/CU (vs 1 before). Partials alias the dead S buffer.
// ---------------------------------------------------------------------------
__global__ __launch_bounds__(256) void apply_partial_kernel(
    const unsigned short* __restrict__ P, const unsigned short* __restrict__ VhT,
    const unsigned short* __restrict__ V2hT, const unsigned short* __restrict__ V2lT,
    float* __restrict__ accm_p, float* __restrict__ acc2_p)
{
    __shared__ __align__(16) unsigned short P_s[128 * 40];
    __shared__ __align__(16) unsigned short Vh_s[64 * 40];
    __shared__ __align__(16) unsigned short V2h_s[64 * 40];
    __shared__ __align__(16) unsigned short V2l_s[64 * 40];
    const int tid = threadIdx.x;
    const int c0 = blockIdx.x * 64, n0 = blockIdx.y * 128;
    const int z = blockIdx.z;
    const int w = tid >> 6, lane = tid & 63;
    const int wrow = w >> 1, wcol = w & 1;
    const int lr = lane & 15, q = lane >> 4;
    f32x4 accm[4][2], acc2[4][2];
    #pragma unroll
    for (int i = 0; i < 4; ++i)
        #pragma unroll
        for (int j = 0; j < 2; ++j) {
            accm[i][j] = (f32x4){0.f, 0.f, 0.f, 0.f};
            acc2[i][j] = (f32x4){0.f, 0.f, 0.f, 0.f};
        }

    const int mbeg = z * (M / MSPLIT);
    for (int mc = mbeg; mc < mbeg + M / MSPLIT; mc += 32) {
        __syncthreads();
        #pragma unroll
        for (int it = 0; it < 2; ++it) {
            int idx = tid + it * 256;
            int row = idx >> 2, seg = idx & 3;
            *(float4*)&P_s[row * 40 + seg * 8] =
                *(const float4*)&P[(size_t)(n0 + row) * M + mc + seg * 8];
        }
        {
            int row = tid >> 2, seg = tid & 3;
            int ldso = row * 40 + seg * 8;
            size_t go = (size_t)(c0 + row) * M + mc + seg * 8;
            *(float4*)&Vh_s[ldso]  = *(const float4*)&VhT[go];
            *(float4*)&V2h_s[ldso] = *(const float4*)&V2hT[go];
            *(float4*)&V2l_s[ldso] = *(const float4*)&V2lT[go];
        }
        __syncthreads();
        short8 a[4], bmat[2], b2h[2], b2l[2];
        #pragma unroll
        for (int i = 0; i < 4; ++i)
            a[i] = *(const short8*)&P_s[(wrow * 64 + i * 16 + lr) * 40 + q * 8];
        #pragma unroll
        for (int j = 0; j < 2; ++j) {
            int co = (wcol * 32 + j * 16 + lr) * 40 + q * 8;
            bmat[j] = *(const short8*)&Vh_s[co];
            b2h[j]  = *(const short8*)&V2h_s[co];
            b2l[j]  = *(const short8*)&V2l_s[co];
        }
        #pragma unroll
        for (int i = 0; i < 4; ++i)
            #pragma unroll
            for (int j = 0; j < 2; ++j) {
                accm[i][j] = mfma_bf16(a[i], bmat[j], accm[i][j]);
                acc2[i][j] = mfma_bf16(a[i], b2h[j],  acc2[i][j]);
                acc2[i][j] = mfma_bf16(a[i], b2l[j],  acc2[i][j]);
            }
    }
    const size_t pbase = (size_t)z * N * C;
    #pragma unroll
    for (int i = 0; i < 4; ++i) {
        int nb = n0 + wrow * 64 + i * 16 + q * 4;
        #pragma unroll
        for (int j = 0; j < 2; ++j) {
            int c = c0 + wcol * 32 + j * 16 + lr;
            #pragma unroll
            for (int r = 0; r < 4; ++r) {
                size_t off = pbase + (size_t)(nb + r) * C + c;
                accm_p[off] = accm[i][j][r];
                acc2_p[off] = acc2[i][j][r];
            }
        }
    }
}

// ---------------------------------------------------------------------------
// K4b: combine partials -> mean/std (fp32). One float4 of c per thread.
// ---------------------------------------------------------------------------
__global__ __launch_bounds__(256) void combine_kernel(
    const float* __restrict__ accm_p, const float* __restrict__ acc2_p,
    const float* __restrict__ rsum, float* __restrict__ meanw,
    float* __restrict__ stdw)
{
    const size_t idx = ((size_t)blockIdx.x * 256 + threadIdx.x) * 4;
    const int n = (int)(idx >> 9);        // /C (C=512)
    const float inv = 1.0f / rsum[n];
    float sm[4] = {0.f, 0.f, 0.f, 0.f}, s2[4] = {0.f, 0.f, 0.f, 0.f};
    #pragma unroll
    for (int z = 0; z < MSPLIT; ++z) {
        float4 a = *(const float4*)&accm_p[(size_t)z * N * C + idx];
        float4 b = *(const float4*)&acc2_p[(size_t)z * N * C + idx];
        sm[0] += a.x; sm[1] += a.y; sm[2] += a.z; sm[3] += a.w;
        s2[0] += b.x; s2[1] += b.y; s2[2] += b.z; s2[3] += b.w;
    }
    float4 mnv, sdv;
    float* mp = (float*)&mnv;
    float* sp = (float*)&sdv;
    #pragma unroll
    for (int k = 0; k < 4; ++k) {
        float mn = sm[k] * inv;
        float m2 = s2[k] * inv;
        mp[k] = mn;
        sp[k] = sqrtf(fmaxf(m2 - mn * mn, 0.f));
    }
    *(float4*)&meanw[idx] = mnv;
    *(float4*)&stdw[idx]  = sdv;
}

// ---------------------------------------------------------------------------
// K5: instance-norm stats per channel (fp32)
// ---------------------------------------------------------------------------
__global__ __launch_bounds__(256) void mvn_kernel(
    const float* __restrict__ content, float* __restrict__ mu, float* __restrict__ rstd)
{
    const int c = blockIdx.x;
    const int tid = threadIdx.x;
    const float* row = content + (size_t)c * N;
    float s = 0.f, ss = 0.f;
    for (int i = tid; i < N; i += 256) {
        float v = row[i];
        s += v;
        ss = fmaf(v, v, ss);
    }
    #pragma unroll
    for (int off = 32; off > 0; off >>= 1) {
        s  += __shfl_xor(s,  off, 64);
        ss += __shfl_xor(ss, off, 64);
    }
    __shared__ float rs[4], rss[4];
    const int wid = tid >> 6, lane = tid & 63;
    if (lane == 0) { rs[wid] = s; rss[wid] = ss; }
    __syncthreads();
    if (tid == 0) {
        float st = rs[0] + rs[1] + rs[2] + rs[3];
        float sst = rss[0] + rss[1] + rss[2] + rss[3];
        float m = st / (float)N;
        float var = (sst - st * st / (float)N) / (float)(N - 1);
        mu[c] = m;
        rstd[c] = rsqrtf(var + 1e-5f);
    }
}

// ---------------------------------------------------------------------------
// K6: final combine (fp32)
// ---------------------------------------------------------------------------
__global__ __launch_bounds__(256) void final_kernel(
    const float* __restrict__ content, const float* __restrict__ meanw,
    const float* __restrict__ stdw, const float* __restrict__ mu,
    const float* __restrict__ rstd, float* __restrict__ out)
{
    __shared__ float mn_s[32][33], sd_s[32][33];
    const int tid = threadIdx.x;
    const int n0 = blockIdx.x * 32;
    const int c0 = blockIdx.y * 32;
    const int tx = tid & 31, ty = tid >> 5;
    #pragma unroll
    for (int i = 0; i < 4; ++i) {
        int n = ty + i * 8;
        mn_s[tx][n] = meanw[(size_t)(n0 + n) * C + c0 + tx];
        sd_s[tx][n] = stdw [(size_t)(n0 + n) * C + c0 + tx];
    }
    __syncthreads();
    #pragma unroll
    for (int i = 0; i < 4; ++i) {
        int c = ty + i * 8;
        float m = mu[c0 + c], r = rstd[c0 + c];
        size_t off = (size_t)(c0 + c) * N + n0 + tx;
        float x = content[off];
        out[off] = sd_s[c][tx] * (x - m) * r + mn_s[c][tx];
    }
}

// ---------------------------------------------------------------------------
extern "C" void kernel_launch(void* const* d_in, const int* in_sizes, int n_in,
                              void* d_out, int out_size, void* d_ws, size_t ws_size,
                              hipStream_t stream)
{
    const float* content = (const float*)d_in[0];
    const float* style   = (const float*)d_in[1];
    const float* ckey    = (const float*)d_in[2];
    const float* skey    = (const float*)d_in[3];
    const float* Wf      = (const float*)d_in[4];
    const float* bf      = (const float*)d_in[5];
    const float* Wg      = (const float*)d_in[6];
    const float* bg      = (const float*)d_in[7];
    const float* Wh      = (const float*)d_in[8];
    const float* bh      = (const float*)d_in[9];
    float* out = (float*)d_out;

    const size_t sz_w  = (size_t)512 * 512 * 2;      // one W half
    const size_t sz_S  = (size_t)N * M * 4;          // 64 MB (aliased by partials)
    const size_t sz_FG = (size_t)N * C * 2;
    const size_t sz_P  = (size_t)N * M * 2;
    const size_t sz_V  = (size_t)C * M * 2;

    char* p = (char*)d_ws;
    auto alloc = [&](size_t bytes) {
        char* r = p;
        p += (bytes + 255) & ~(size_t)255;
        return r;
    };
    unsigned short* WfH = (unsigned short*)alloc(sz_w);
    unsigned short* WfL = (unsigned short*)alloc(sz_w);
    unsigned short* WgH = (unsigned short*)alloc(sz_w);
    unsigned short* WgL = (unsigned short*)alloc(sz_w);
    unsigned short* WhH = (unsigned short*)alloc(sz_w);
    unsigned short* WhL = (unsigned short*)alloc(sz_w);
    float* S = (float*)alloc(sz_S);                  // also: partial accm/acc2
    unsigned short* Fh = (unsigned short*)alloc(sz_FG);
    unsigned short* Fl = (unsigned short*)alloc(sz_FG);
    unsigned short* Gh = (unsigned short*)alloc(sz_FG);
    unsigned short* Gl = (unsigned short*)alloc(sz_FG);
    unsigned short* P    = (unsigned short*)alloc(sz_P);
    unsigned short* VhT  = (unsigned short*)alloc(sz_V);
    unsigned short* V2hT = (unsigned short*)alloc(sz_V);
    unsigned short* V2lT = (unsigned short*)alloc(sz_V);
    float* rsum  = (float*)alloc((size_t)N * 4);
    float* meanw = (float*)alloc((size_t)N * C * 4);
    float* stdw  = (float*)alloc((size_t)N * C * 4);
    float* mu    = (float*)alloc((size_t)C * 4);
    float* rstd  = (float*)alloc((size_t)C * 4);

    // partials alias S (dead between rowstat and next batch's logits):
    // accm_p = MSPLIT*N*C floats, acc2_p = MSPLIT*N*C floats = exactly N*M
    float* accm_p = S;
    float* acc2_p = S + (size_t)MSPLIT * N * C;

    wsplit_kernel<<<dim3(1024), 256, 0, stream>>>(Wf, WfH, WfL);
    wsplit_kernel<<<dim3(1024), 256, 0, stream>>>(Wg, WgH, WgL);
    wsplit_kernel<<<dim3(1024), 256, 0, stream>>>(Wh, WhH, WhL);

    for (int b = 0; b < BATCH; ++b) {
        const size_t fo = (size_t)b * C * N;
        linear_fg_mfma<<<dim3(N / 64, C / 64), 256, 0, stream>>>(ckey + fo, WfH, WfL, bf, Fh, Fl);
        linear_fg_mfma<<<dim3(M / 64, C / 64), 256, 0, stream>>>(skey + fo, WgH, WgL, bg, Gh, Gl);
        linear_v_mfma<<<dim3(M / 64, C / 64), 256, 0, stream>>>(style + fo, WhH, WhL, bh,
                                                                VhT, V2hT, V2lT);
        logits_mfma_kernel<<<dim3(M / 128, N / 128), 256, 0, stream>>>(Fh, Fl, Gh, Gl, S);
        rowstat_p_kernel<<<dim3(N), 256, 0, stream>>>(S, P, rsum);
        apply_partial_kernel<<<dim3(C / 64, N / 128, MSPLIT), 256, 0, stream>>>(
            P, VhT, V2hT, V2lT, accm_p, acc2_p);
        combine_kernel<<<dim3(N * C / 1024), 256, 0, stream>>>(
            accm_p, acc2_p, rsum, meanw, stdw);
        mvn_kernel<<<dim3(C), 256, 0, stream>>>(content + fo, mu, rstd);
        final_kernel<<<dim3(N / 32, C / 32), 256, 0, stream>>>(
            content + fo, meanw, stdw, mu, rstd, out + fo);
    }
}